// Round 1
// baseline (603.307 us; speedup 1.0000x reference)
//
#include <hip/hip_runtime.h>

#define HID 2048
#define NE 64
#define NTOK 32768        // GROUPS * TOKENS = 4 * 8192
#define CAP 160
#define GAP_THR 1e-3f

// ---------------------------------------------------------------------------
// K1: logits GEMM + softmax-max + top-2.  Block = 512 thr = 8 waves.
// Wave w handles H-slice [w*256, w*256+256) for 64 tokens (token = lane).
// W reads are wave-uniform (s_load path); partials reduced via LDS atomics.
// ---------------------------------------------------------------------------
__global__ __launch_bounds__(512, 4) void k_logits(
    const float* __restrict__ A, const float* __restrict__ W,
    const float* __restrict__ bias,
    float* __restrict__ logits, float* __restrict__ probsmax,
    int* __restrict__ choice, int* __restrict__ idx2o, float* __restrict__ gapo)
{
    __shared__ float lacc[64][65];   // +1 pad: conflict-free row access
    const int tid = threadIdx.x;
    for (int i = tid; i < 64 * 65; i += 512) ((float*)lacc)[i] = 0.0f;
    __syncthreads();

    const int wv   = __builtin_amdgcn_readfirstlane(tid >> 6);  // 0..7, uniform
    const int lane = tid & 63;
    const int tok0 = blockIdx.x * 64;
    const float* a     = A + (size_t)(tok0 + lane) * HID + wv * 256;
    const float* wbase = W + wv * 256;

    float acc[NE];
#pragma unroll
    for (int e = 0; e < NE; ++e) acc[e] = 0.0f;

#pragma unroll 1
    for (int h0 = 0; h0 < 256; h0 += 16) {
        float av[16];
#pragma unroll
        for (int i = 0; i < 4; ++i) {
            float4 t4 = *(const float4*)(a + h0 + 4 * i);
            av[4*i+0] = t4.x; av[4*i+1] = t4.y; av[4*i+2] = t4.z; av[4*i+3] = t4.w;
        }
#pragma unroll
        for (int e = 0; e < NE; ++e) {
            const float* wp = wbase + e * HID + h0;   // uniform address -> s_load
#pragma unroll
            for (int i = 0; i < 16; ++i)
                acc[e] = fmaf(av[i], wp[i], acc[e]);
        }
    }

#pragma unroll
    for (int e = 0; e < NE; ++e)
        atomicAdd(&lacc[lane][e], acc[e]);           // ds_add_f32
    __syncthreads();

    // parallel logits store: 512 threads x 8 floats, fully coalesced
    {
        const int t  = tid >> 3;
        const int c8 = (tid & 7) * 8;
        float v[8];
#pragma unroll
        for (int i = 0; i < 8; ++i) v[i] = lacc[t][c8 + i] + bias[c8 + i];
        float* lp = logits + (size_t)(tok0 + t) * NE + c8;
        *(float4*)(lp)     = make_float4(v[0], v[1], v[2], v[3]);
        *(float4*)(lp + 4) = make_float4(v[4], v[5], v[6], v[7]);
    }

    // per-token epilogue on wave 0: top-2 + softmax denominator
    if (tid < 64) {
        const int t = tid;
        float m1 = -3.4e38f, m2 = -3.4e38f;
        int i1 = 0, i2 = 0;
#pragma unroll
        for (int e = 0; e < NE; ++e) {
            const float vv = lacc[t][e] + bias[e];
            if (vv > m1)      { m2 = m1; i2 = i1; m1 = vv; i1 = e; }
            else if (vv > m2) { m2 = vv; i2 = e; }
        }
        float s = 0.0f;
#pragma unroll
        for (int e = 0; e < NE; ++e)
            s += __expf(lacc[t][e] + bias[e] - m1);
        const int g2 = tok0 + t;
        probsmax[g2] = 1.0f / s;       // max prob = exp(0)/sum
        choice[g2]   = i1;
        idx2o[g2]    = i2;
        gapo[g2]     = m1 - m2;
    }
}

// ---------------------------------------------------------------------------
// K1b: fp64 refinement of near-tie argmax (matches the f64 np reference).
// ---------------------------------------------------------------------------
__global__ void k_refine(const float* __restrict__ A, const float* __restrict__ W,
                         const float* __restrict__ bias,
                         int* __restrict__ choice, const int* __restrict__ idx2,
                         const float* __restrict__ gap)
{
    const int gt = blockIdx.x * blockDim.x + threadIdx.x;
    if (gt >= NTOK) return;
    if (!(gap[gt] < GAP_THR)) return;
    const int i1 = choice[gt], i2 = idx2[gt];
    if (i1 == i2) return;
    const float* a  = A + (size_t)gt * HID;
    const float* w1 = W + (size_t)i1 * HID;
    const float* w2 = W + (size_t)i2 * HID;
    double d1 = (double)bias[i1], d2 = (double)bias[i2];
    for (int h = 0; h < HID; ++h) {
        const double av = (double)a[h];
        d1 += av * (double)w1[h];
        d2 += av * (double)w2[h];
    }
    if (d2 > d1 || (d2 == d1 && i2 < i1)) choice[gt] = i2;
}

// ---------------------------------------------------------------------------
// K2: per-64-token-chunk histogram of expert choices (wave ballot).
// 512 chunks total; chunks never straddle groups (64 | 8192).
// ---------------------------------------------------------------------------
__global__ void k_count(const int* __restrict__ choice, int* __restrict__ cnt)
{
    const int lane  = threadIdx.x & 63;
    const int wave  = threadIdx.x >> 6;
    const int chunk = blockIdx.x * 4 + wave;   // 0..511
    const int gt    = chunk * 64 + lane;
    const int c     = choice[gt];
    int mycnt = 0;
#pragma unroll 1
    for (int e = 0; e < NE; ++e) {
        const unsigned long long m = __ballot(c == e);
        if (lane == e) mycnt = (int)__popcll(m);
    }
    cnt[chunk * 64 + lane] = mycnt;
}

// ---------------------------------------------------------------------------
// K3: exclusive scan of chunk histograms along the 128 chunks of each group.
// ---------------------------------------------------------------------------
__global__ void k_scan(const int* __restrict__ cnt, int* __restrict__ off)
{
    const int g = blockIdx.x;     // 0..3
    const int e = threadIdx.x;    // 0..63
    int run = 0;
    for (int c = 0; c < 128; ++c) {
        const int idx = (g * 128 + c) * 64 + e;
        const int v = cnt[idx];
        off[idx] = run;
        run += v;
    }
}

// ---------------------------------------------------------------------------
// K4: emit expert_index rows (0/1 as fp32) with capacity mask.
// priority = chunk_offset + in-chunk ballot prefix + 1  (inclusive cumsum).
// ---------------------------------------------------------------------------
__global__ void k_emit(const int* __restrict__ choice, const int* __restrict__ off,
                       float* __restrict__ eout)
{
    const int lane  = threadIdx.x & 63;
    const int wave  = threadIdx.x >> 6;
    const int chunk = blockIdx.x * 4 + wave;
    const int gt    = chunk * 64 + lane;
    const int c     = choice[gt];
    unsigned long long mymask = 0;
#pragma unroll 1
    for (int e = 0; e < NE; ++e) {
        const unsigned long long m = __ballot(c == e);
        if (c == e) mymask = m;
    }
    const int pre  = (int)__popcll(mymask & ((1ull << lane) - 1ull));
    const int base = off[chunk * 64 + c];
    const float val = (base + pre + 1 <= CAP) ? 1.0f : 0.0f;
    float* op = eout + (size_t)gt * NE;
#pragma unroll
    for (int i = 0; i < 16; ++i) {
        float4 v;
        v.x = (4*i+0 == c) ? val : 0.0f;
        v.y = (4*i+1 == c) ? val : 0.0f;
        v.z = (4*i+2 == c) ? val : 0.0f;
        v.w = (4*i+3 == c) ? val : 0.0f;
        ((float4*)op)[i] = v;
    }
}

// ---------------------------------------------------------------------------
extern "C" void kernel_launch(void* const* d_in, const int* in_sizes, int n_in,
                              void* d_out, int out_size, void* d_ws, size_t ws_size,
                              hipStream_t stream) {
    const float* A = (const float*)d_in[0];   // [4, 8192, 2048]
    const float* W = (const float*)d_in[1];   // [64, 2048]
    const float* b = (const float*)d_in[2];   // [64]

    float* out        = (float*)d_out;
    float* expert_out = out;                        // 2,097,152
    float* probsmax   = out + 2097152;              //    32,768
    float* logits     = out + 2097152 + 32768;      // 2,097,152

    char* ws    = (char*)d_ws;
    int*   choice = (int*)(ws);                 // 128 KB
    int*   idx2   = (int*)(ws + 131072);        // 128 KB
    float* gap    = (float*)(ws + 262144);      // 128 KB
    int*   cnt    = (int*)(ws + 393216);        // 128 KB
    int*   off    = (int*)(ws + 524288);        // 128 KB

    hipLaunchKernelGGL(k_logits, dim3(512), dim3(512), 0, stream,
                       A, W, b, logits, probsmax, choice, idx2, gap);
    hipLaunchKernelGGL(k_refine, dim3(128), dim3(256), 0, stream,
                       A, W, b, choice, idx2, gap);
    hipLaunchKernelGGL(k_count, dim3(128), dim3(256), 0, stream, choice, cnt);
    hipLaunchKernelGGL(k_scan, dim3(4), dim3(64), 0, stream, cnt, off);
    hipLaunchKernelGGL(k_emit, dim3(128), dim3(256), 0, stream, choice, off, expert_out);
}